// Round 1
// baseline (368.782 us; speedup 1.0000x reference)
//
#include <hip/hip_runtime.h>
#include <hip/hip_bf16.h>

// B=32, N=1024, D=768, H=12, d=64. Real tokens M=32768.
// Pad token handled analytically: ksum += 1.0 per component, kv/output unaffected.

typedef __bf16 bf16x8 __attribute__((ext_vector_type(8)));
typedef float f32x4 __attribute__((ext_vector_type(4)));

__device__ __forceinline__ ushort f2bf(float f) {
  union { float f; unsigned u; } x; x.f = f;
  unsigned r = x.u + 0x7fffu + ((x.u >> 16) & 1u);   // RNE
  return (ushort)(r >> 16);
}
__device__ __forceinline__ float bf2f(ushort h) {
  union { unsigned u; float f; } x; x.u = ((unsigned)h) << 16;
  return x.f;
}
__device__ __forceinline__ void gload_lds16(const void* g, void* lds) {
  __builtin_amdgcn_global_load_lds((const __attribute__((address_space(1))) void*)g,
                                   (__attribute__((address_space(3))) void*)lds, 16, 0, 0);
}

// ---------------- fp32 -> bf16 elementwise (x4 vectorized) ----------------
__global__ __launch_bounds__(256) void cvt_f32_bf16(const float* __restrict__ in,
                                                    ushort* __restrict__ out, int n4) {
  int i = blockIdx.x * 256 + threadIdx.x;
  if (i >= n4) return;
  float4 v = reinterpret_cast<const float4*>(in)[i];
  ushort4 o;
  o.x = f2bf(v.x); o.y = f2bf(v.y); o.z = f2bf(v.z); o.w = f2bf(v.w);
  reinterpret_cast<ushort4*>(out)[i] = o;
}

// ---------------- transpose+convert: src[R][C] f32 -> dst[C][R] bf16 ----------------
__global__ __launch_bounds__(256) void transpose_cvt(const float* __restrict__ src,
                                                     ushort* __restrict__ dst, int R, int C) {
  __shared__ float tile[32][33];
  int bc = blockIdx.x * 32, br = blockIdx.y * 32;
  int tx = threadIdx.x & 31, ty = threadIdx.x >> 5;   // 32x8
  #pragma unroll
  for (int i = 0; i < 32; i += 8)
    tile[ty + i][tx] = src[(size_t)(br + ty + i) * C + (bc + tx)];
  __syncthreads();
  #pragma unroll
  for (int i = 0; i < 32; i += 8)
    dst[(size_t)(bc + ty + i) * R + (br + tx)] = f2bf(tile[tx][ty + i]);
}

// ---------------- GEMM: C[M][N] = A[M][K] * Bt[N][K]^T  (bf16 in, fp32 accum) -------
// MODE 0: epilogue phi(x)=elu(x)+1 on cols<1536 (q,k), store bf16 (qkv buffer)
// MODE 1: epilogue +bias, store fp32 (final output)
template <int MODE>
__global__ __launch_bounds__(256) void gemm_bt(const ushort* __restrict__ A,
                                               const ushort* __restrict__ Bt,
                                               void* __restrict__ C,
                                               const float* __restrict__ bias,
                                               int M, int N, int K) {
  __shared__ ushort As[128 * 32];
  __shared__ ushort Bs[128 * 32];
  const int tid = threadIdx.x;
  const int lane = tid & 63;
  const int wm = tid >> 7, wn = (tid >> 6) & 1;       // 2x2 wave grid, 64x64 each
  const int m0 = blockIdx.y * 128, n0 = blockIdx.x * 128;
  f32x4 acc[4][4] = {};
  const int nk = K >> 5;                              // K/32
  const int row = tid >> 2, kc = tid & 3;             // 16B chunk: 4 chunks per 32-elem row
  for (int kt = 0; kt < nk; ++kt) {
    __syncthreads();
    const int kb = kt * 32 + kc * 8;
    gload_lds16(A + (size_t)(m0 + row) * K + kb,        &As[tid * 8]);
    gload_lds16(A + (size_t)(m0 + row + 64) * K + kb,   &As[(tid + 256) * 8]);
    gload_lds16(Bt + (size_t)(n0 + row) * K + kb,       &Bs[tid * 8]);
    gload_lds16(Bt + (size_t)(n0 + row + 64) * K + kb,  &Bs[(tid + 256) * 8]);
    asm volatile("s_waitcnt vmcnt(0)" ::: "memory");
    __syncthreads();
    bf16x8 a[4], b[4];
    #pragma unroll
    for (int i = 0; i < 4; ++i) {
      a[i] = *reinterpret_cast<const bf16x8*>(&As[(wm * 64 + i * 16 + (lane & 15)) * 32 + (lane >> 4) * 8]);
      b[i] = *reinterpret_cast<const bf16x8*>(&Bs[(wn * 64 + i * 16 + (lane & 15)) * 32 + (lane >> 4) * 8]);
    }
    #pragma unroll
    for (int i = 0; i < 4; ++i)
      #pragma unroll
      for (int j = 0; j < 4; ++j)
        acc[i][j] = __builtin_amdgcn_mfma_f32_16x16x32_bf16(a[i], b[j], acc[i][j], 0, 0, 0);
  }
  // epilogue: C/D layout col=lane&15, row=(lane>>4)*4+r (verified m89/m91)
  #pragma unroll
  for (int i = 0; i < 4; ++i) {
    const int grow0 = m0 + wm * 64 + i * 16 + ((lane >> 4) << 2);
    #pragma unroll
    for (int j = 0; j < 4; ++j) {
      const int gcol = n0 + wn * 64 + j * 16 + (lane & 15);
      #pragma unroll
      for (int r = 0; r < 4; ++r) {
        float v = acc[i][j][r];
        if (MODE == 0) {
          if (gcol < 1536) v = (v > 0.f) ? (v + 1.f) : __expf(v);   // phi on q,k
          reinterpret_cast<ushort*>(C)[(size_t)(grow0 + r) * N + gcol] = f2bf(v);
        } else {
          reinterpret_cast<float*>(C)[(size_t)(grow0 + r) * N + gcol] = v + bias[gcol];
        }
      }
    }
  }
}

// ---------------- kv partial: per (b,h,s-split) outer-product accumulation ----------
// kv_part[sp][bh][m][dq] = sum_s v[s][m]*k[s][dq]  ;  ks_part[sp][bh][dq] = sum_s k[s][dq]
__global__ __launch_bounds__(256) void kv_partial(const ushort* __restrict__ qkv,
                                                  float* __restrict__ kv_part,
                                                  float* __restrict__ ks_part) {
  const int blk = blockIdx.x;          // 384*4
  const int bh = blk >> 2, sp = blk & 3;
  const int b = bh / 12, h = bh % 12;
  const int tid = threadIdx.x;
  __shared__ ushort Ks[32 * 64];
  __shared__ ushort Vs[32 * 64];
  float acc[4][4] = {};                // [m][dq]
  float kacc[4] = {};
  const int dq0 = (tid & 15) * 4, mq0 = (tid >> 4) * 4;
  const int r = tid >> 3, o = tid & 7;
  for (int st = 0; st < 256; st += 32) {
    const int s0 = sp * 256 + st;
    __syncthreads();
    const size_t rowbase = (size_t)(b * 1024 + s0 + r) * 2304 + h * 64 + o * 8;
    gload_lds16(qkv + rowbase + 768,  &Ks[tid * 8]);
    gload_lds16(qkv + rowbase + 1536, &Vs[tid * 8]);
    asm volatile("s_waitcnt vmcnt(0)" ::: "memory");
    __syncthreads();
    #pragma unroll 8
    for (int s = 0; s < 32; ++s) {
      short4 kk = *reinterpret_cast<const short4*>(&Ks[s * 64 + dq0]);
      short4 vv = *reinterpret_cast<const short4*>(&Vs[s * 64 + mq0]);
      float kf[4] = { bf2f((ushort)kk.x), bf2f((ushort)kk.y), bf2f((ushort)kk.z), bf2f((ushort)kk.w) };
      float vf[4] = { bf2f((ushort)vv.x), bf2f((ushort)vv.y), bf2f((ushort)vv.z), bf2f((ushort)vv.w) };
      #pragma unroll
      for (int jm = 0; jm < 4; ++jm)
        #pragma unroll
        for (int id = 0; id < 4; ++id)
          acc[jm][id] += vf[jm] * kf[id];
      if (mq0 == 0) {
        #pragma unroll
        for (int id = 0; id < 4; ++id) kacc[id] += kf[id];
      }
    }
  }
  float* kvp = kv_part + ((size_t)sp * 384 + bh) * 4096;
  #pragma unroll
  for (int jm = 0; jm < 4; ++jm)
    #pragma unroll
    for (int id = 0; id < 4; ++id)
      kvp[(mq0 + jm) * 64 + dq0 + id] = acc[jm][id];
  if (mq0 == 0) {
    #pragma unroll
    for (int id = 0; id < 4; ++id)
      ks_part[((size_t)sp * 384 + bh) * 64 + dq0 + id] = kacc[id];
  }
}

// ---------------- reduce splits: kv -> bf16 [bh][m][dq], ksum += 1.0 (pad token) ----
__global__ __launch_bounds__(256) void kv_reduce(const float* __restrict__ kv_part,
                                                 const float* __restrict__ ks_part,
                                                 ushort* __restrict__ kv_bf,
                                                 float* __restrict__ ksum) {
  int i = blockIdx.x * 256 + threadIdx.x;
  if (i < 384 * 4096) {
    float s = 0.f;
    #pragma unroll
    for (int p = 0; p < 4; ++p) s += kv_part[(size_t)p * (384 * 4096) + i];
    kv_bf[i] = f2bf(s);
  }
  if (i < 384 * 64) {
    float s = 1.0f;    // phi(0)=1 contribution of the zero padding token
    #pragma unroll
    for (int p = 0; p < 4; ++p) s += ks_part[(size_t)p * (384 * 64) + i];
    ksum[i] = s;
  }
}

// ---------------- attention: out[t][h*64+m] = z[t] * sum_dq q[t][dq]*kv[dq][m] -------
__global__ __launch_bounds__(256) void attn_kernel(const ushort* __restrict__ qkv,
                                                   const ushort* __restrict__ kv_bf,
                                                   const float* __restrict__ ksum,
                                                   ushort* __restrict__ attn) {
  const int blk = blockIdx.x;          // 384*8
  const int bh = blk >> 3, tb = blk & 7;
  const int b = bh / 12, h = bh % 12;
  const int row0 = b * 1024 + tb * 128;
  __shared__ ushort Qs[128 * 64];
  __shared__ ushort KVs[64 * 64];      // [m][dq]
  __shared__ float zs[128];
  __shared__ float ks_lds[64];
  const int tid = threadIdx.x;
  const int lane = tid & 63, w = tid >> 6;
  #pragma unroll
  for (int j = 0; j < 4; ++j) {
    int c = j * 256 + tid;
    gload_lds16(qkv + (size_t)(row0 + (c >> 3)) * 2304 + h * 64 + (c & 7) * 8, &Qs[c * 8]);
  }
  #pragma unroll
  for (int j = 0; j < 2; ++j) {
    int c = j * 256 + tid;
    gload_lds16(kv_bf + (size_t)bh * 4096 + c * 8, &KVs[c * 8]);
  }
  if (tid < 64) ks_lds[tid] = ksum[bh * 64 + tid];
  asm volatile("s_waitcnt vmcnt(0)" ::: "memory");
  __syncthreads();
  if (tid < 128) {
    float d = 0.f;
    #pragma unroll 8
    for (int e = 0; e < 64; ++e) d += bf2f(Qs[tid * 64 + e]) * ks_lds[e];
    zs[tid] = 1.f / (d + 1e-6f);
  }
  __syncthreads();
  f32x4 acc[2][4] = {};
  #pragma unroll
  for (int ks = 0; ks < 2; ++ks) {
    bf16x8 a[2], bb[4];
    #pragma unroll
    for (int i = 0; i < 2; ++i)
      a[i] = *reinterpret_cast<const bf16x8*>(&Qs[(w * 32 + i * 16 + (lane & 15)) * 64 + ks * 32 + (lane >> 4) * 8]);
    #pragma unroll
    for (int j = 0; j < 4; ++j)
      bb[j] = *reinterpret_cast<const bf16x8*>(&KVs[(j * 16 + (lane & 15)) * 64 + ks * 32 + (lane >> 4) * 8]);
    #pragma unroll
    for (int i = 0; i < 2; ++i)
      #pragma unroll
      for (int j = 0; j < 4; ++j)
        acc[i][j] = __builtin_amdgcn_mfma_f32_16x16x32_bf16(a[i], bb[j], acc[i][j], 0, 0, 0);
  }
  #pragma unroll
  for (int i = 0; i < 2; ++i) {
    const int t0 = w * 32 + i * 16 + ((lane >> 4) << 2);
    #pragma unroll
    for (int j = 0; j < 4; ++j) {
      const int m = j * 16 + (lane & 15);
      #pragma unroll
      for (int r = 0; r < 4; ++r) {
        float v = acc[i][j][r] * zs[t0 + r];
        attn[(size_t)(row0 + t0 + r) * 768 + h * 64 + m] = f2bf(v);
      }
    }
  }
}

// ---------------- launch ----------------
extern "C" void kernel_launch(void* const* d_in, const int* in_sizes, int n_in,
                              void* d_out, int out_size, void* d_ws, size_t ws_size,
                              hipStream_t stream) {
  (void)in_sizes; (void)n_in; (void)out_size; (void)ws_size;
  const float* x    = (const float*)d_in[0];
  const float* Wqkv = (const float*)d_in[1];
  const float* Wout = (const float*)d_in[2];
  const float* bout = (const float*)d_in[3];
  float* out = (float*)d_out;
  char* ws = (char*)d_ws;

  // workspace layout (total ~210 MB); region 0 is reused by 3 time-disjoint buffers
  ushort* xbf    = (ushort*)(ws);               // 50,331,648 B : x bf16 [32768][768]
  ushort* wqkvT  = (ushort*)(ws + 50331648);    //  3,538,944 B : W_qkv^T bf16 [2304][768]
  ushort* woutT  = (ushort*)(ws + 53870592);    //  1,179,648 B : W_out^T bf16 [768][768]
  ushort* qkv    = (ushort*)(ws + 55050240);    // 150,994,944 B: phi(q)|phi(k)|v bf16 [32768][2304]
  float*  ksp    = (float*) (ws + 206045184);   //    393,216 B : ksum partials [4][384][64]
  ushort* kvbf   = (ushort*)(ws + 206438400);   //  3,145,728 B : kv bf16 [384][64m][64dq]
  float*  ksum   = (float*) (ws + 209584128);   //     98,304 B : ksum+1 [384][64]
  float*  kvpart = (float*)(ws);                // 25,165,824 B : overlays xbf (dead after gemm1)
  ushort* attn   = (ushort*)(ws);               // 50,331,648 B : overlays kvpart (dead after kv_reduce)

  cvt_f32_bf16<<<24576, 256, 0, stream>>>(x, xbf, 6291456);
  transpose_cvt<<<dim3(72, 24), 256, 0, stream>>>(Wqkv, wqkvT, 768, 2304);
  transpose_cvt<<<dim3(24, 24), 256, 0, stream>>>(Wout, woutT, 768, 768);
  gemm_bt<0><<<dim3(18, 256), 256, 0, stream>>>(xbf, wqkvT, qkv, nullptr, 32768, 2304, 768);
  kv_partial<<<1536, 256, 0, stream>>>(qkv, kvpart, ksp);
  kv_reduce<<<6144, 256, 0, stream>>>(kvpart, ksp, kvbf, ksum);
  attn_kernel<<<3072, 256, 0, stream>>>(qkv, kvbf, ksum, attn);
  gemm_bt<1><<<dim3(6, 256), 256, 0, stream>>>(attn, woutT, out, bout, 32768, 768, 768);
}

// Round 2
// 318.616 us; speedup vs baseline: 1.1574x; 1.1574x over previous
//
#include <hip/hip_runtime.h>
#include <hip/hip_bf16.h>

// B=32, N=1024, D=768, H=12, d=64. Real tokens M=32768.
// Pad token handled analytically: ksum += 1.0 per component, kv/output unaffected.

typedef __bf16 bf16x8 __attribute__((ext_vector_type(8)));
typedef float f32x4 __attribute__((ext_vector_type(4)));

__device__ __forceinline__ ushort f2bf(float f) {
  union { float f; unsigned u; } x; x.f = f;
  unsigned r = x.u + 0x7fffu + ((x.u >> 16) & 1u);   // RNE
  return (ushort)(r >> 16);
}
__device__ __forceinline__ float bf2f(ushort h) {
  union { unsigned u; float f; } x; x.u = ((unsigned)h) << 16;
  return x.f;
}
__device__ __forceinline__ void gload_lds16(const void* g, void* lds) {
  __builtin_amdgcn_global_load_lds((const __attribute__((address_space(1))) void*)g,
                                   (__attribute__((address_space(3))) void*)lds, 16, 0, 0);
}

// ---------------- fp32 -> bf16 elementwise (x4 vectorized) ----------------
__global__ __launch_bounds__(256) void cvt_f32_bf16(const float* __restrict__ in,
                                                    ushort* __restrict__ out, int n4) {
  int i = blockIdx.x * 256 + threadIdx.x;
  if (i >= n4) return;
  float4 v = reinterpret_cast<const float4*>(in)[i];
  ushort4 o;
  o.x = f2bf(v.x); o.y = f2bf(v.y); o.z = f2bf(v.z); o.w = f2bf(v.w);
  reinterpret_cast<ushort4*>(out)[i] = o;
}

// ---------------- transpose+convert: src[R][C] f32 -> dst[C][R] bf16 ----------------
__global__ __launch_bounds__(256) void transpose_cvt(const float* __restrict__ src,
                                                     ushort* __restrict__ dst, int R, int C) {
  __shared__ float tile[32][33];
  int bc = blockIdx.x * 32, br = blockIdx.y * 32;
  int tx = threadIdx.x & 31, ty = threadIdx.x >> 5;   // 32x8
  #pragma unroll
  for (int i = 0; i < 32; i += 8)
    tile[ty + i][tx] = src[(size_t)(br + ty + i) * C + (bc + tx)];
  __syncthreads();
  #pragma unroll
  for (int i = 0; i < 32; i += 8)
    dst[(size_t)(bc + ty + i) * R + (br + tx)] = f2bf(tile[tx][ty + i]);
}

// ==================== 256x256 phase-scheduled GEMM ====================
// C[M][N] = A[M][K] * Bt[N][K]^T, bf16 in, fp32 accum.
// 512 threads = 8 waves (2 M x 4 N), per-wave 128x64 out, BK=64.
// LDS 128 KiB dynamic: 2 bufs x { A[2ks][256][32] , B[2ks][256][32] }, XOR-swizzled slots.
// Schedule per K-tile: 4 phases (ks, rowhalf); H(t+1,0)={A,B k0} staged at P1,
// H(t+1,1) at P3; vmcnt(4) at P2/P4 end (counted, never 0 in steady state).
// MODE 0: epilogue phi on cols<1536, store bf16.  MODE 1: +bias, store fp32.
template <int MODE>
__global__ __launch_bounds__(512, 2) void gemm256(const ushort* __restrict__ A,
                                                  const ushort* __restrict__ Bt,
                                                  void* __restrict__ C,
                                                  const float* __restrict__ bias,
                                                  int N, int K, int nbx, int cpx) {
  extern __shared__ ushort lds[];
  const int tid = threadIdx.x;
  const int lane = tid & 63;
  const int wid = tid >> 6;
  const int wm = wid >> 2, wn = wid & 3;
  const int laneR = lane & 15, laneS = lane >> 4;

  // XCD-bijective swizzle (nwg % 8 == 0), bx-fastest within chunk
  const int bid = blockIdx.x;
  const int lin = (bid & 7) * cpx + (bid >> 3);
  const int by = lin / nbx, bx = lin - by * nbx;
  const int m0 = by * 256, n0 = bx * 256;
  const int NT = K >> 6;

  // staging constants: thread covers row sr (+128 per issue), 16B slot ss
  const int sr = tid >> 2, ss = tid & 3;
  const int sslot = ss ^ ((tid >> 3) & 3);                   // inverse-swizzled source slot
  const ushort* Asrc0 = A + (size_t)(m0 + sr) * K + sslot * 8;
  const ushort* Bsrc0 = Bt + (size_t)(n0 + sr) * K + sslot * 8;
  const size_t rowstep = (size_t)128 * K;
  const int ldst0 = tid * 8;                                 // ushort offset, +4096 per issue

  // ds_read constants: swizzled slot is a per-lane constant (row ≡ laneR mod 8)
  const int sprime = laneS ^ ((laneR >> 1) & 3);
  const int aoff = (wm * 128 + laneR) * 32 + sprime * 8;     // + ks*8192 + frag*512
  const int boff = 16384 + (wn * 64 + laneR) * 32 + sprime * 8;

  f32x4 acc[8][4] = {};

  // ---- prologue: stage tile 0 -> buf0, full drain once ----
  #pragma unroll
  for (int ks = 0; ks < 2; ++ks)
    #pragma unroll
    for (int i = 0; i < 2; ++i) {
      gload_lds16(Asrc0 + ks * 32 + (size_t)i * rowstep, lds + ks * 8192 + i * 4096 + ldst0);
      gload_lds16(Bsrc0 + ks * 32 + (size_t)i * rowstep, lds + 16384 + ks * 8192 + i * 4096 + ldst0);
    }
  asm volatile("s_waitcnt vmcnt(0)" ::: "memory");
  __builtin_amdgcn_s_barrier();
  asm volatile("" ::: "memory");

  for (int t = 0; t < NT; ++t) {
    const int cur = t & 1;
    const ushort* __restrict__ buf = lds + cur * 32768;
    ushort* __restrict__ nbuf = lds + (cur ^ 1) * 32768;
    const int kt1 = (t + 1) << 6;
    const bool pre = (t + 1 < NT);
    bf16x8 bfr[4], afr[4];
    #pragma unroll
    for (int ks = 0; ks < 2; ++ks) {
      #pragma unroll
      for (int rh = 0; rh < 2; ++rh) {
        // --- phase top: ds reads for this phase's 16 MFMA
        if (rh == 0) {
          #pragma unroll
          for (int j = 0; j < 4; ++j)
            bfr[j] = *(const bf16x8*)(buf + ks * 8192 + boff + j * 512);
        }
        #pragma unroll
        for (int ii = 0; ii < 4; ++ii)
          afr[ii] = *(const bf16x8*)(buf + ks * 8192 + aoff + (rh * 4 + ii) * 512);
        // --- stage issue: P1 -> H(t+1,0)=k0 halves, P3 -> H(t+1,1)=k1 halves
        if (rh == 0 && pre) {
          #pragma unroll
          for (int i = 0; i < 2; ++i) {
            gload_lds16(Asrc0 + kt1 + ks * 32 + (size_t)i * rowstep,
                        nbuf + ks * 8192 + i * 4096 + ldst0);
            gload_lds16(Bsrc0 + kt1 + ks * 32 + (size_t)i * rowstep,
                        nbuf + 16384 + ks * 8192 + i * 4096 + ldst0);
          }
        }
        // --- counted waits: P2-end guarantees H(t,1); P4-end guarantees H(t+1,0)
        if (rh == 1) {
          if (ks == 0) {
            if (pre) asm volatile("s_waitcnt vmcnt(4)" ::: "memory");
            else     asm volatile("s_waitcnt vmcnt(0)" ::: "memory");
          } else if (pre) {
            asm volatile("s_waitcnt vmcnt(4)" ::: "memory");
          }
        }
        __builtin_amdgcn_sched_barrier(0);
        __builtin_amdgcn_s_barrier();
        asm volatile("" ::: "memory");
        __builtin_amdgcn_sched_barrier(0);
        __builtin_amdgcn_s_setprio(1);
        #pragma unroll
        for (int ii = 0; ii < 4; ++ii)
          #pragma unroll
          for (int j = 0; j < 4; ++j)
            acc[rh * 4 + ii][j] =
                __builtin_amdgcn_mfma_f32_16x16x32_bf16(afr[ii], bfr[j], acc[rh * 4 + ii][j], 0, 0, 0);
        __builtin_amdgcn_s_setprio(0);
        __builtin_amdgcn_sched_barrier(0);
        asm volatile("" ::: "memory");
        __builtin_amdgcn_s_barrier();
      }
    }
  }

  // ---- epilogue: C/D layout col=lane&15, row=(lane>>4)*4+r ----
  #pragma unroll
  for (int i = 0; i < 8; ++i) {
    const int grow0 = m0 + wm * 128 + i * 16 + (laneS << 2);
    #pragma unroll
    for (int j = 0; j < 4; ++j) {
      const int gcol = n0 + wn * 64 + j * 16 + laneR;
      #pragma unroll
      for (int r = 0; r < 4; ++r) {
        float v = acc[i][j][r];
        if (MODE == 0) {
          if (gcol < 1536) v = (v > 0.f) ? (v + 1.f) : __expf(v);   // phi on q,k
          reinterpret_cast<ushort*>(C)[(size_t)(grow0 + r) * N + gcol] = f2bf(v);
        } else {
          reinterpret_cast<float*>(C)[(size_t)(grow0 + r) * N + gcol] = v + bias[gcol];
        }
      }
    }
  }
}

// ---------------- kv partial: per (b,h,s-split) outer-product accumulation ----------
__global__ __launch_bounds__(256) void kv_partial(const ushort* __restrict__ qkv,
                                                  float* __restrict__ kv_part,
                                                  float* __restrict__ ks_part) {
  const int blk = blockIdx.x;          // 384*4
  const int bh = blk >> 2, sp = blk & 3;
  const int b = bh / 12, h = bh % 12;
  const int tid = threadIdx.x;
  __shared__ ushort Ks[32 * 64];
  __shared__ ushort Vs[32 * 64];
  float acc[4][4] = {};                // [m][dq]
  float kacc[4] = {};
  const int dq0 = (tid & 15) * 4, mq0 = (tid >> 4) * 4;
  const int r = tid >> 3, o = tid & 7;
  for (int st = 0; st < 256; st += 32) {
    const int s0 = sp * 256 + st;
    __syncthreads();
    const size_t rowbase = (size_t)(b * 1024 + s0 + r) * 2304 + h * 64 + o * 8;
    gload_lds16(qkv + rowbase + 768,  &Ks[tid * 8]);
    gload_lds16(qkv + rowbase + 1536, &Vs[tid * 8]);
    asm volatile("s_waitcnt vmcnt(0)" ::: "memory");
    __syncthreads();
    #pragma unroll 8
    for (int s = 0; s < 32; ++s) {
      short4 kk = *reinterpret_cast<const short4*>(&Ks[s * 64 + dq0]);
      short4 vv = *reinterpret_cast<const short4*>(&Vs[s * 64 + mq0]);
      float kf[4] = { bf2f((ushort)kk.x), bf2f((ushort)kk.y), bf2f((ushort)kk.z), bf2f((ushort)kk.w) };
      float vf[4] = { bf2f((ushort)vv.x), bf2f((ushort)vv.y), bf2f((ushort)vv.z), bf2f((ushort)vv.w) };
      #pragma unroll
      for (int jm = 0; jm < 4; ++jm)
        #pragma unroll
        for (int id = 0; id < 4; ++id)
          acc[jm][id] += vf[jm] * kf[id];
      if (mq0 == 0) {
        #pragma unroll
        for (int id = 0; id < 4; ++id) kacc[id] += kf[id];
      }
    }
  }
  float* kvp = kv_part + ((size_t)sp * 384 + bh) * 4096;
  #pragma unroll
  for (int jm = 0; jm < 4; ++jm)
    #pragma unroll
    for (int id = 0; id < 4; ++id)
      kvp[(mq0 + jm) * 64 + dq0 + id] = acc[jm][id];
  if (mq0 == 0) {
    #pragma unroll
    for (int id = 0; id < 4; ++id)
      ks_part[((size_t)sp * 384 + bh) * 64 + dq0 + id] = kacc[id];
  }
}

// ---------------- reduce splits: kv -> bf16 [bh][m][dq], ksum += 1.0 (pad token) ----
__global__ __launch_bounds__(256) void kv_reduce(const float* __restrict__ kv_part,
                                                 const float* __restrict__ ks_part,
                                                 ushort* __restrict__ kv_bf,
                                                 float* __restrict__ ksum) {
  int i = blockIdx.x * 256 + threadIdx.x;
  if (i < 384 * 4096) {
    float s = 0.f;
    #pragma unroll
    for (int p = 0; p < 4; ++p) s += kv_part[(size_t)p * (384 * 4096) + i];
    kv_bf[i] = f2bf(s);
  }
  if (i < 384 * 64) {
    float s = 1.0f;    // phi(0)=1 contribution of the zero padding token
    #pragma unroll
    for (int p = 0; p < 4; ++p) s += ks_part[(size_t)p * (384 * 64) + i];
    ksum[i] = s;
  }
}

// ---------------- attention: out[t][h*64+m] = z[t] * sum_dq q[t][dq]*kv[dq][m] -------
__global__ __launch_bounds__(256) void attn_kernel(const ushort* __restrict__ qkv,
                                                   const ushort* __restrict__ kv_bf,
                                                   const float* __restrict__ ksum,
                                                   ushort* __restrict__ attn) {
  const int blk = blockIdx.x;          // 384*8
  const int bh = blk >> 3, tb = blk & 7;
  const int b = bh / 12, h = bh % 12;
  const int row0 = b * 1024 + tb * 128;
  __shared__ ushort Qs[128 * 64];
  __shared__ ushort KVs[64 * 64];      // [m][dq]
  __shared__ float zs[128];
  __shared__ float ks_lds[64];
  const int tid = threadIdx.x;
  const int lane = tid & 63, w = tid >> 6;
  #pragma unroll
  for (int j = 0; j < 4; ++j) {
    int c = j * 256 + tid;
    gload_lds16(qkv + (size_t)(row0 + (c >> 3)) * 2304 + h * 64 + (c & 7) * 8, &Qs[c * 8]);
  }
  #pragma unroll
  for (int j = 0; j < 2; ++j) {
    int c = j * 256 + tid;
    gload_lds16(kv_bf + (size_t)bh * 4096 + c * 8, &KVs[c * 8]);
  }
  if (tid < 64) ks_lds[tid] = ksum[bh * 64 + tid];
  asm volatile("s_waitcnt vmcnt(0)" ::: "memory");
  __syncthreads();
  if (tid < 128) {
    float d = 0.f;
    #pragma unroll 8
    for (int e = 0; e < 64; ++e) d += bf2f(Qs[tid * 64 + e]) * ks_lds[e];
    zs[tid] = 1.f / (d + 1e-6f);
  }
  __syncthreads();
  f32x4 acc[2][4] = {};
  #pragma unroll
  for (int ks = 0; ks < 2; ++ks) {
    bf16x8 a[2], bb[4];
    #pragma unroll
    for (int i = 0; i < 2; ++i)
      a[i] = *reinterpret_cast<const bf16x8*>(&Qs[(w * 32 + i * 16 + (lane & 15)) * 64 + ks * 32 + (lane >> 4) * 8]);
    #pragma unroll
    for (int j = 0; j < 4; ++j)
      bb[j] = *reinterpret_cast<const bf16x8*>(&KVs[(j * 16 + (lane & 15)) * 64 + ks * 32 + (lane >> 4) * 8]);
    #pragma unroll
    for (int i = 0; i < 2; ++i)
      #pragma unroll
      for (int j = 0; j < 4; ++j)
        acc[i][j] = __builtin_amdgcn_mfma_f32_16x16x32_bf16(a[i], bb[j], acc[i][j], 0, 0, 0);
  }
  #pragma unroll
  for (int i = 0; i < 2; ++i) {
    const int t0 = w * 32 + i * 16 + ((lane >> 4) << 2);
    #pragma unroll
    for (int j = 0; j < 4; ++j) {
      const int m = j * 16 + (lane & 15);
      #pragma unroll
      for (int r = 0; r < 4; ++r) {
        float v = acc[i][j][r] * zs[t0 + r];
        attn[(size_t)(row0 + t0 + r) * 768 + h * 64 + m] = f2bf(v);
      }
    }
  }
}

// ---------------- launch ----------------
extern "C" void kernel_launch(void* const* d_in, const int* in_sizes, int n_in,
                              void* d_out, int out_size, void* d_ws, size_t ws_size,
                              hipStream_t stream) {
  (void)in_sizes; (void)n_in; (void)out_size; (void)ws_size;
  const float* x    = (const float*)d_in[0];
  const float* Wqkv = (const float*)d_in[1];
  const float* Wout = (const float*)d_in[2];
  const float* bout = (const float*)d_in[3];
  float* out = (float*)d_out;
  char* ws = (char*)d_ws;

  // workspace layout (total ~210 MB); region 0 is reused by 3 time-disjoint buffers
  ushort* xbf    = (ushort*)(ws);               // 50,331,648 B : x bf16 [32768][768]
  ushort* wqkvT  = (ushort*)(ws + 50331648);    //  3,538,944 B : W_qkv^T bf16 [2304][768]
  ushort* woutT  = (ushort*)(ws + 53870592);    //  1,179,648 B : W_out^T bf16 [768][768]
  ushort* qkv    = (ushort*)(ws + 55050240);    // 150,994,944 B: phi(q)|phi(k)|v bf16 [32768][2304]
  float*  ksp    = (float*) (ws + 206045184);   //    393,216 B : ksum partials [4][384][64]
  ushort* kvbf   = (ushort*)(ws + 206438400);   //  3,145,728 B : kv bf16 [384][64m][64dq]
  float*  ksum   = (float*) (ws + 209584128);   //     98,304 B : ksum+1 [384][64]
  float*  kvpart = (float*)(ws);                // 25,165,824 B : overlays xbf (dead after gemm1)
  ushort* attn   = (ushort*)(ws);               // 50,331,648 B : overlays kvpart (dead after kv_reduce)

  static const int LDS_BYTES = 131072;
  hipFuncSetAttribute(reinterpret_cast<const void*>(&gemm256<0>),
                      hipFuncAttributeMaxDynamicSharedMemorySize, LDS_BYTES);
  hipFuncSetAttribute(reinterpret_cast<const void*>(&gemm256<1>),
                      hipFuncAttributeMaxDynamicSharedMemorySize, LDS_BYTES);

  cvt_f32_bf16<<<24576, 256, 0, stream>>>(x, xbf, 6291456);
  transpose_cvt<<<dim3(72, 24), 256, 0, stream>>>(Wqkv, wqkvT, 768, 2304);
  transpose_cvt<<<dim3(24, 24), 256, 0, stream>>>(Wout, woutT, 768, 768);
  // GEMM1: M=32768 (nby=128), N=2304 (nbx=9) -> nwg=1152, cpx=144
  gemm256<0><<<1152, 512, LDS_BYTES, stream>>>(xbf, wqkvT, qkv, nullptr, 2304, 768, 9, 144);
  kv_partial<<<1536, 256, 0, stream>>>(qkv, kvpart, ksp);
  kv_reduce<<<6144, 256, 0, stream>>>(kvpart, ksp, kvbf, ksum);
  attn_kernel<<<3072, 256, 0, stream>>>(qkv, kvbf, ksum, attn);
  // GEMM2: M=32768 (nby=128), N=768 (nbx=3) -> nwg=384, cpx=48
  gemm256<1><<<384, 512, LDS_BYTES, stream>>>(attn, woutT, out, bout, 768, 768, 3, 48);
}

// Round 3
// 316.828 us; speedup vs baseline: 1.1640x; 1.0056x over previous
//
#include <hip/hip_runtime.h>
#include <hip/hip_bf16.h>

// B=32, N=1024, D=768, H=12, d=64. Real tokens M=32768.
// Pad token handled analytically: ksum += 1.0 per component, kv/output unaffected.

typedef __bf16 bf16x8 __attribute__((ext_vector_type(8)));
typedef float f32x4 __attribute__((ext_vector_type(4)));

__device__ __forceinline__ ushort f2bf(float f) {
  union { float f; unsigned u; } x; x.f = f;
  unsigned r = x.u + 0x7fffu + ((x.u >> 16) & 1u);   // RNE
  return (ushort)(r >> 16);
}
__device__ __forceinline__ float bf2f(ushort h) {
  union { unsigned u; float f; } x; x.u = ((unsigned)h) << 16;
  return x.f;
}
__device__ __forceinline__ void gload_lds16(const void* g, void* lds) {
  __builtin_amdgcn_global_load_lds((const __attribute__((address_space(1))) void*)g,
                                   (__attribute__((address_space(3))) void*)lds, 16, 0, 0);
}

// ---------------- fp32 -> bf16 elementwise (x4 vectorized) ----------------
__global__ __launch_bounds__(256) void cvt_f32_bf16(const float* __restrict__ in,
                                                    ushort* __restrict__ out, int n4) {
  int i = blockIdx.x * 256 + threadIdx.x;
  if (i >= n4) return;
  float4 v = reinterpret_cast<const float4*>(in)[i];
  ushort4 o;
  o.x = f2bf(v.x); o.y = f2bf(v.y); o.z = f2bf(v.z); o.w = f2bf(v.w);
  reinterpret_cast<ushort4*>(out)[i] = o;
}

// ---------------- transpose+convert: src[R][C] f32 -> dst[C][R] bf16 ----------------
__global__ __launch_bounds__(256) void transpose_cvt(const float* __restrict__ src,
                                                     ushort* __restrict__ dst, int R, int C) {
  __shared__ float tile[32][33];
  int bc = blockIdx.x * 32, br = blockIdx.y * 32;
  int tx = threadIdx.x & 31, ty = threadIdx.x >> 5;   // 32x8
  #pragma unroll
  for (int i = 0; i < 32; i += 8)
    tile[ty + i][tx] = src[(size_t)(br + ty + i) * C + (bc + tx)];
  __syncthreads();
  #pragma unroll
  for (int i = 0; i < 32; i += 8)
    dst[(size_t)(bc + ty + i) * R + (br + tx)] = f2bf(tile[tx][ty + i]);
}

// ==================== 256x256 phase-scheduled GEMM (m201-style) ====================
// C[M][N] = A[M][K] * Bt[N][K]^T, bf16 in, fp32 accum.
// 512 threads = 8 waves (2M x 4N), per-wave 128x64 out, BK=64, NT=K/64 tiles.
// LDS 128 KiB: 2 bufs x { A[2ks][256][32] , B[2ks][256][32] }, XOR slot swizzle.
// Half-tile (HT) = one matrix's ks-half (256x32 = 2 loads/thread). Issue stream:
//   tile t p0: A-k1(t+1)->nbuf | p1: B-k1(t+1)->nbuf | p2: A-k0(t+2)->cbuf(k0 dead)
//   | p3: B-k0(t+2)->cbuf.  Each HT lands 5-6 phases before first read.
// Waits: vmcnt(8) at p1-end (confirms k1(t), read at p2) and p3-end (confirms
// k0(t+1), read at t+1 p0). Uniform incl. prologue/clamped tail; never 0 in loop.
// MODE 0: epilogue phi on cols<1536, store bf16.  MODE 1: +bias, store fp32.
template <int MODE>
__global__ __launch_bounds__(512, 2) void gemm256(const ushort* __restrict__ A,
                                                  const ushort* __restrict__ Bt,
                                                  void* __restrict__ C,
                                                  const float* __restrict__ bias,
                                                  int N, int K, int nbx, int cpx) {
  extern __shared__ ushort lds[];
  const int tid = threadIdx.x;
  const int lane = tid & 63;
  const int wid = tid >> 6;
  const int wm = wid >> 2, wn = wid & 3;
  const int laneR = lane & 15, laneS = lane >> 4;

  // XCD-bijective swizzle (nwg % 8 == 0), bx-fastest within chunk
  const int bid = blockIdx.x;
  const int lin = (bid & 7) * cpx + (bid >> 3);
  const int by = lin / nbx, bx = lin - by * nbx;
  const int m0 = by * 256, n0 = bx * 256;
  const int NT = K >> 6;

  // staging: thread covers row sr (+128 for 2nd load), 16B slot ss (inverse-swizzled)
  const int sr = tid >> 2, ss = tid & 3;
  const int sslot = ss ^ ((sr >> 1) & 3);
  const ushort* Asrc0 = A + (size_t)(m0 + sr) * K + sslot * 8;
  const ushort* Bsrc0 = Bt + (size_t)(n0 + sr) * K + sslot * 8;
  const size_t rowstep = (size_t)128 * K;
  const int ldst0 = tid * 8;

  // ds_read: swizzled slot is a per-lane constant (row ≡ laneR mod 8)
  const int sprime = laneS ^ ((laneR >> 1) & 3);
  const int aoff = (wm * 128 + laneR) * 32 + sprime * 8;     // + ks*8192 + frag*512
  const int boff = 16384 + (wn * 64 + laneR) * 32 + sprime * 8;

  f32x4 acc[8][4] = {};

  // stage one half-tile: matrix src, k-tile kt, ks-half, dest buffer region
  #define STAGE_HT(SRC, KT, KS, DST)                                              \
    { gload_lds16((SRC) + (KT) * 64 + (KS) * 32,                                  \
                  (DST) + (KS) * 8192 + ldst0);                                   \
      gload_lds16((SRC) + (KT) * 64 + (KS) * 32 + rowstep,                        \
                  (DST) + (KS) * 8192 + 4096 + ldst0); }

  // ---- prologue: k0(0), k1(0), k0(1) in order; confirm k0(0) via vmcnt(8) ----
  {
    ushort* b0 = lds;
    ushort* b1 = lds + 32768;
    STAGE_HT(Asrc0, 0, 0, b0);              // loads 1-2
    STAGE_HT(Bsrc0, 0, 0, b0 + 16384);      // 3-4
    STAGE_HT(Asrc0, 0, 1, b0);              // 5-6
    STAGE_HT(Bsrc0, 0, 1, b0 + 16384);      // 7-8
    STAGE_HT(Asrc0, 1, 0, b1);              // 9-10
    STAGE_HT(Bsrc0, 1, 0, b1 + 16384);      // 11-12
  }
  asm volatile("s_waitcnt vmcnt(8)" ::: "memory");
  __builtin_amdgcn_sched_barrier(0);
  __builtin_amdgcn_s_barrier();
  __builtin_amdgcn_sched_barrier(0);

  for (int t = 0; t < NT; ++t) {
    ushort* cbuf = lds + (t & 1) * 32768;
    ushort* nbuf = lds + ((t & 1) ^ 1) * 32768;
    const int t1 = (t + 1 < NT) ? t + 1 : t;   // clamped: tail stages are dead stores
    const int t2 = (t + 2 < NT) ? t + 2 : t;
    bf16x8 afr[4], bfr[4];

    // ================ p0: ks0, ih0 ================
    #pragma unroll
    for (int j = 0; j < 4; ++j)
      bfr[j] = *(const bf16x8*)(cbuf + boff + j * 512);
    #pragma unroll
    for (int ii = 0; ii < 4; ++ii)
      afr[ii] = *(const bf16x8*)(cbuf + aoff + ii * 512);
    STAGE_HT(Asrc0, t1, 1, nbuf);                       // A-k1(t+1)
    __builtin_amdgcn_sched_barrier(0);
    __builtin_amdgcn_s_barrier();
    __builtin_amdgcn_s_setprio(1);
    #pragma unroll
    for (int ii = 0; ii < 4; ++ii)
      #pragma unroll
      for (int j = 0; j < 4; ++j)
        acc[ii][j] = __builtin_amdgcn_mfma_f32_16x16x32_bf16(afr[ii], bfr[j], acc[ii][j], 0, 0, 0);
    __builtin_amdgcn_s_setprio(0);
    __builtin_amdgcn_s_barrier();
    __builtin_amdgcn_sched_barrier(0);

    // ================ p1: ks0, ih1 ================
    #pragma unroll
    for (int ii = 0; ii < 4; ++ii)
      afr[ii] = *(const bf16x8*)(cbuf + aoff + (4 + ii) * 512);
    STAGE_HT(Bsrc0, t1, 1, nbuf + 16384);               // B-k1(t+1)
    asm volatile("s_waitcnt vmcnt(8)" ::: "memory");    // confirms k1(t) (read at p2)
    __builtin_amdgcn_sched_barrier(0);
    __builtin_amdgcn_s_barrier();
    __builtin_amdgcn_s_setprio(1);
    #pragma unroll
    for (int ii = 0; ii < 4; ++ii)
      #pragma unroll
      for (int j = 0; j < 4; ++j)
        acc[4 + ii][j] = __builtin_amdgcn_mfma_f32_16x16x32_bf16(afr[ii], bfr[j], acc[4 + ii][j], 0, 0, 0);
    __builtin_amdgcn_s_setprio(0);
    __builtin_amdgcn_s_barrier();
    __builtin_amdgcn_sched_barrier(0);

    // ================ p2: ks1, ih0 ================
    #pragma unroll
    for (int j = 0; j < 4; ++j)
      bfr[j] = *(const bf16x8*)(cbuf + 8192 + boff + j * 512);
    #pragma unroll
    for (int ii = 0; ii < 4; ++ii)
      afr[ii] = *(const bf16x8*)(cbuf + 8192 + aoff + ii * 512);
    STAGE_HT(Asrc0, t2, 0, cbuf);                       // A-k0(t+2) into cur k0 (dead)
    __builtin_amdgcn_sched_barrier(0);
    __builtin_amdgcn_s_barrier();
    __builtin_amdgcn_s_setprio(1);
    #pragma unroll
    for (int ii = 0; ii < 4; ++ii)
      #pragma unroll
      for (int j = 0; j < 4; ++j)
        acc[ii][j] = __builtin_amdgcn_mfma_f32_16x16x32_bf16(afr[ii], bfr[j], acc[ii][j], 0, 0, 0);
    __builtin_amdgcn_s_setprio(0);
    __builtin_amdgcn_s_barrier();
    __builtin_amdgcn_sched_barrier(0);

    // ================ p3: ks1, ih1 ================
    #pragma unroll
    for (int ii = 0; ii < 4; ++ii)
      afr[ii] = *(const bf16x8*)(cbuf + 8192 + aoff + (4 + ii) * 512);
    STAGE_HT(Bsrc0, t2, 0, cbuf + 16384);               // B-k0(t+2)
    asm volatile("s_waitcnt vmcnt(8)" ::: "memory");    // confirms k0(t+1) (read at t+1 p0)
    __builtin_amdgcn_sched_barrier(0);
    __builtin_amdgcn_s_barrier();
    __builtin_amdgcn_s_setprio(1);
    #pragma unroll
    for (int ii = 0; ii < 4; ++ii)
      #pragma unroll
      for (int j = 0; j < 4; ++j)
        acc[4 + ii][j] = __builtin_amdgcn_mfma_f32_16x16x32_bf16(afr[ii], bfr[j], acc[4 + ii][j], 0, 0, 0);
    __builtin_amdgcn_s_setprio(0);
    __builtin_amdgcn_s_barrier();
    __builtin_amdgcn_sched_barrier(0);
  }
  #undef STAGE_HT
  asm volatile("s_waitcnt vmcnt(0)" ::: "memory");      // drain dead tail stages

  // ---- epilogue: C/D layout col=lane&15, row=(lane>>4)*4+r ----
  #pragma unroll
  for (int i = 0; i < 8; ++i) {
    const int grow0 = m0 + wm * 128 + i * 16 + (laneS << 2);
    #pragma unroll
    for (int j = 0; j < 4; ++j) {
      const int gcol = n0 + wn * 64 + j * 16 + laneR;
      #pragma unroll
      for (int r = 0; r < 4; ++r) {
        float v = acc[i][j][r];
        if (MODE == 0) {
          if (gcol < 1536) v = (v > 0.f) ? (v + 1.f) : __expf(v);   // phi on q,k
          reinterpret_cast<ushort*>(C)[(size_t)(grow0 + r) * N + gcol] = f2bf(v);
        } else {
          reinterpret_cast<float*>(C)[(size_t)(grow0 + r) * N + gcol] = v + bias[gcol];
        }
      }
    }
  }
}

// ---------------- kv partial: per (b,h,s-split) outer-product accumulation ----------
__global__ __launch_bounds__(256) void kv_partial(const ushort* __restrict__ qkv,
                                                  float* __restrict__ kv_part,
                                                  float* __restrict__ ks_part) {
  const int blk = blockIdx.x;          // 384*4
  const int bh = blk >> 2, sp = blk & 3;
  const int b = bh / 12, h = bh % 12;
  const int tid = threadIdx.x;
  __shared__ ushort Ks[32 * 64];
  __shared__ ushort Vs[32 * 64];
  float acc[4][4] = {};                // [m][dq]
  float kacc[4] = {};
  const int dq0 = (tid & 15) * 4, mq0 = (tid >> 4) * 4;
  const int r = tid >> 3, o = tid & 7;
  for (int st = 0; st < 256; st += 32) {
    const int s0 = sp * 256 + st;
    __syncthreads();
    const size_t rowbase = (size_t)(b * 1024 + s0 + r) * 2304 + h * 64 + o * 8;
    gload_lds16(qkv + rowbase + 768,  &Ks[tid * 8]);
    gload_lds16(qkv + rowbase + 1536, &Vs[tid * 8]);
    asm volatile("s_waitcnt vmcnt(0)" ::: "memory");
    __syncthreads();
    #pragma unroll 8
    for (int s = 0; s < 32; ++s) {
      short4 kk = *reinterpret_cast<const short4*>(&Ks[s * 64 + dq0]);
      short4 vv = *reinterpret_cast<const short4*>(&Vs[s * 64 + mq0]);
      float kf[4] = { bf2f((ushort)kk.x), bf2f((ushort)kk.y), bf2f((ushort)kk.z), bf2f((ushort)kk.w) };
      float vf[4] = { bf2f((ushort)vv.x), bf2f((ushort)vv.y), bf2f((ushort)vv.z), bf2f((ushort)vv.w) };
      #pragma unroll
      for (int jm = 0; jm < 4; ++jm)
        #pragma unroll
        for (int id = 0; id < 4; ++id)
          acc[jm][id] += vf[jm] * kf[id];
      if (mq0 == 0) {
        #pragma unroll
        for (int id = 0; id < 4; ++id) kacc[id] += kf[id];
      }
    }
  }
  float* kvp = kv_part + ((size_t)sp * 384 + bh) * 4096;
  #pragma unroll
  for (int jm = 0; jm < 4; ++jm)
    #pragma unroll
    for (int id = 0; id < 4; ++id)
      kvp[(mq0 + jm) * 64 + dq0 + id] = acc[jm][id];
  if (mq0 == 0) {
    #pragma unroll
    for (int id = 0; id < 4; ++id)
      ks_part[((size_t)sp * 384 + bh) * 64 + dq0 + id] = kacc[id];
  }
}

// ---------------- reduce splits: kv -> bf16 [bh][m][dq], ksum += 1.0 (pad token) ----
__global__ __launch_bounds__(256) void kv_reduce(const float* __restrict__ kv_part,
                                                 const float* __restrict__ ks_part,
                                                 ushort* __restrict__ kv_bf,
                                                 float* __restrict__ ksum) {
  int i = blockIdx.x * 256 + threadIdx.x;
  if (i < 384 * 4096) {
    float s = 0.f;
    #pragma unroll
    for (int p = 0; p < 4; ++p) s += kv_part[(size_t)p * (384 * 4096) + i];
    kv_bf[i] = f2bf(s);
  }
  if (i < 384 * 64) {
    float s = 1.0f;    // phi(0)=1 contribution of the zero padding token
    #pragma unroll
    for (int p = 0; p < 4; ++p) s += ks_part[(size_t)p * (384 * 64) + i];
    ksum[i] = s;
  }
}

// ---------------- attention: out[t][h*64+m] = z[t] * sum_dq q[t][dq]*kv[dq][m] -------
__global__ __launch_bounds__(256) void attn_kernel(const ushort* __restrict__ qkv,
                                                   const ushort* __restrict__ kv_bf,
                                                   const float* __restrict__ ksum,
                                                   ushort* __restrict__ attn) {
  const int blk = blockIdx.x;          // 384*8
  const int bh = blk >> 3, tb = blk & 7;
  const int b = bh / 12, h = bh % 12;
  const int row0 = b * 1024 + tb * 128;
  __shared__ ushort Qs[128 * 64];
  __shared__ ushort KVs[64 * 64];      // [m][dq]
  __shared__ float zs[128];
  __shared__ float ks_lds[64];
  const int tid = threadIdx.x;
  const int lane = tid & 63, w = tid >> 6;
  #pragma unroll
  for (int j = 0; j < 4; ++j) {
    int c = j * 256 + tid;
    gload_lds16(qkv + (size_t)(row0 + (c >> 3)) * 2304 + h * 64 + (c & 7) * 8, &Qs[c * 8]);
  }
  #pragma unroll
  for (int j = 0; j < 2; ++j) {
    int c = j * 256 + tid;
    gload_lds16(kv_bf + (size_t)bh * 4096 + c * 8, &KVs[c * 8]);
  }
  if (tid < 64) ks_lds[tid] = ksum[bh * 64 + tid];
  asm volatile("s_waitcnt vmcnt(0)" ::: "memory");
  __syncthreads();
  if (tid < 128) {
    float d = 0.f;
    #pragma unroll 8
    for (int e = 0; e < 64; ++e) d += bf2f(Qs[tid * 64 + e]) * ks_lds[e];
    zs[tid] = 1.f / (d + 1e-6f);
  }
  __syncthreads();
  f32x4 acc[2][4] = {};
  #pragma unroll
  for (int ks = 0; ks < 2; ++ks) {
    bf16x8 a[2], bb[4];
    #pragma unroll
    for (int i = 0; i < 2; ++i)
      a[i] = *reinterpret_cast<const bf16x8*>(&Qs[(w * 32 + i * 16 + (lane & 15)) * 64 + ks * 32 + (lane >> 4) * 8]);
    #pragma unroll
    for (int j = 0; j < 4; ++j)
      bb[j] = *reinterpret_cast<const bf16x8*>(&KVs[(j * 16 + (lane & 15)) * 64 + ks * 32 + (lane >> 4) * 8]);
    #pragma unroll
    for (int i = 0; i < 2; ++i)
      #pragma unroll
      for (int j = 0; j < 4; ++j)
        acc[i][j] = __builtin_amdgcn_mfma_f32_16x16x32_bf16(a[i], bb[j], acc[i][j], 0, 0, 0);
  }
  #pragma unroll
  for (int i = 0; i < 2; ++i) {
    const int t0 = w * 32 + i * 16 + ((lane >> 4) << 2);
    #pragma unroll
    for (int j = 0; j < 4; ++j) {
      const int m = j * 16 + (lane & 15);
      #pragma unroll
      for (int r = 0; r < 4; ++r) {
        float v = acc[i][j][r] * zs[t0 + r];
        attn[(size_t)(row0 + t0 + r) * 768 + h * 64 + m] = f2bf(v);
      }
    }
  }
}

// ---------------- launch ----------------
extern "C" void kernel_launch(void* const* d_in, const int* in_sizes, int n_in,
                              void* d_out, int out_size, void* d_ws, size_t ws_size,
                              hipStream_t stream) {
  (void)in_sizes; (void)n_in; (void)out_size; (void)ws_size;
  const float* x    = (const float*)d_in[0];
  const float* Wqkv = (const float*)d_in[1];
  const float* Wout = (const float*)d_in[2];
  const float* bout = (const float*)d_in[3];
  float* out = (float*)d_out;
  char* ws = (char*)d_ws;

  // workspace layout (total ~210 MB); region 0 is reused by 3 time-disjoint buffers
  ushort* xbf    = (ushort*)(ws);               // 50,331,648 B : x bf16 [32768][768]
  ushort* wqkvT  = (ushort*)(ws + 50331648);    //  3,538,944 B : W_qkv^T bf16 [2304][768]
  ushort* woutT  = (ushort*)(ws + 53870592);    //  1,179,648 B : W_out^T bf16 [768][768]
  ushort* qkv    = (ushort*)(ws + 55050240);    // 150,994,944 B: phi(q)|phi(k)|v bf16 [32768][2304]
  float*  ksp    = (float*) (ws + 206045184);   //    393,216 B : ksum partials [4][384][64]
  ushort* kvbf   = (ushort*)(ws + 206438400);   //  3,145,728 B : kv bf16 [384][64m][64dq]
  float*  ksum   = (float*) (ws + 209584128);   //     98,304 B : ksum+1 [384][64]
  float*  kvpart = (float*)(ws);                // 25,165,824 B : overlays xbf (dead after gemm1)
  ushort* attn   = (ushort*)(ws);               // 50,331,648 B : overlays kvpart (dead after kv_reduce)

  static const int LDS_BYTES = 131072;
  hipFuncSetAttribute(reinterpret_cast<const void*>(&gemm256<0>),
                      hipFuncAttributeMaxDynamicSharedMemorySize, LDS_BYTES);
  hipFuncSetAttribute(reinterpret_cast<const void*>(&gemm256<1>),
                      hipFuncAttributeMaxDynamicSharedMemorySize, LDS_BYTES);

  cvt_f32_bf16<<<24576, 256, 0, stream>>>(x, xbf, 6291456);
  transpose_cvt<<<dim3(72, 24), 256, 0, stream>>>(Wqkv, wqkvT, 768, 2304);
  transpose_cvt<<<dim3(24, 24), 256, 0, stream>>>(Wout, woutT, 768, 768);
  // GEMM1: M=32768 (nby=128), N=2304 (nbx=9) -> nwg=1152, cpx=144
  gemm256<0><<<1152, 512, LDS_BYTES, stream>>>(xbf, wqkvT, qkv, nullptr, 2304, 768, 9, 144);
  kv_partial<<<1536, 256, 0, stream>>>(qkv, kvpart, ksp);
  kv_reduce<<<6144, 256, 0, stream>>>(kvpart, ksp, kvbf, ksum);
  attn_kernel<<<3072, 256, 0, stream>>>(qkv, kvbf, ksum, attn);
  // GEMM2: M=32768 (nby=128), N=768 (nbx=3) -> nwg=384, cpx=48
  gemm256<1><<<384, 512, LDS_BYTES, stream>>>(attn, woutT, out, bout, 768, 768, 3, 48);
}

// Round 4
// 315.603 us; speedup vs baseline: 1.1685x; 1.0039x over previous
//
#include <hip/hip_runtime.h>
#include <hip/hip_bf16.h>

// B=32, N=1024, D=768, H=12, d=64. Real tokens M=32768.
// Pad token handled analytically: ksum += 1.0 per component, kv/output unaffected.

typedef __bf16 bf16x8 __attribute__((ext_vector_type(8)));
typedef float f32x4 __attribute__((ext_vector_type(4)));

__device__ __forceinline__ ushort f2bf(float f) {
  union { float f; unsigned u; } x; x.f = f;
  unsigned r = x.u + 0x7fffu + ((x.u >> 16) & 1u);   // RNE
  return (ushort)(r >> 16);
}
__device__ __forceinline__ float bf2f(ushort h) {
  union { unsigned u; float f; } x; x.u = ((unsigned)h) << 16;
  return x.f;
}
__device__ __forceinline__ void gload_lds16(const void* g, void* lds) {
  __builtin_amdgcn_global_load_lds((const __attribute__((address_space(1))) void*)g,
                                   (__attribute__((address_space(3))) void*)lds, 16, 0, 0);
}

// ---------------- fp32 -> bf16 elementwise (x4 vectorized) ----------------
__global__ __launch_bounds__(256) void cvt_f32_bf16(const float* __restrict__ in,
                                                    ushort* __restrict__ out, int n4) {
  int i = blockIdx.x * 256 + threadIdx.x;
  if (i >= n4) return;
  float4 v = reinterpret_cast<const float4*>(in)[i];
  ushort4 o;
  o.x = f2bf(v.x); o.y = f2bf(v.y); o.z = f2bf(v.z); o.w = f2bf(v.w);
  reinterpret_cast<ushort4*>(out)[i] = o;
}

// ---------------- transpose+convert: src[R][C] f32 -> dst[C][R] bf16 ----------------
__global__ __launch_bounds__(256) void transpose_cvt(const float* __restrict__ src,
                                                     ushort* __restrict__ dst, int R, int C) {
  __shared__ float tile[32][33];
  int bc = blockIdx.x * 32, br = blockIdx.y * 32;
  int tx = threadIdx.x & 31, ty = threadIdx.x >> 5;   // 32x8
  #pragma unroll
  for (int i = 0; i < 32; i += 8)
    tile[ty + i][tx] = src[(size_t)(br + ty + i) * C + (bc + tx)];
  __syncthreads();
  #pragma unroll
  for (int i = 0; i < 32; i += 8)
    dst[(size_t)(bc + ty + i) * R + (br + tx)] = f2bf(tile[tx][ty + i]);
}

// ==================== 256x256 phase-scheduled GEMM, fragment-prefetch ====================
// C[M][N] = A[M][K] * Bt[N][K]^T, bf16 in, fp32 accum.
// 512 threads = 8 waves (2M x 4N), per-wave 128x64 out, BK=64, NT=K/64 tiles.
// LDS 128 KiB: 2 bufs x { A[2ks][256][32] , B[2ks][256][32] }, XOR slot swizzle.
// ONE barrier per phase. Each phase: stage 1 HT -> [vmcnt(6) at p0/p2] ->
// prefetch NEXT phase's fragments (ds_read under this phase's MFMA via partial
// lgkm waits) -> MFMA x16 -> barrier. Frag sets X/Y double-buffered in regs.
// Issue stream: p0:A-k1(t+1)->nbuf, p1:B-k1(t+1)->nbuf, p2:A-k0(t+2)->cbuf(k0 dead),
// p3:B-k0(t+2)->cbuf. vmcnt(6) at p0 confirms k1(t) (read at p1); at p2 confirms
// k0(t+1) (read at p3). Uniform incl. prologue and clamped dead-store tail.
// MODE 0: epilogue phi on cols<1536, store bf16.  MODE 1: +bias, store fp32.
template <int MODE>
__global__ __launch_bounds__(512, 2) void gemm256(const ushort* __restrict__ A,
                                                  const ushort* __restrict__ Bt,
                                                  void* __restrict__ C,
                                                  const float* __restrict__ bias,
                                                  int N, int K, int nbx, int cpx) {
  extern __shared__ ushort lds[];
  const int tid = threadIdx.x;
  const int lane = tid & 63;
  const int wid = tid >> 6;
  const int wm = wid >> 2, wn = wid & 3;
  const int laneR = lane & 15, laneS = lane >> 4;

  // XCD-bijective swizzle (nwg % 8 == 0), bx-fastest within chunk
  const int bid = blockIdx.x;
  const int lin = (bid & 7) * cpx + (bid >> 3);
  const int by = lin / nbx, bx = lin - by * nbx;
  const int m0 = by * 256, n0 = bx * 256;
  const int NT = K >> 6;

  // staging: thread covers row sr (+128 for 2nd load), 16B slot ss (inverse-swizzled)
  const int sr = tid >> 2, ss = tid & 3;
  const int sslot = ss ^ ((sr >> 1) & 3);
  const ushort* Asrc0 = A + (size_t)(m0 + sr) * K + sslot * 8;
  const ushort* Bsrc0 = Bt + (size_t)(n0 + sr) * K + sslot * 8;
  const size_t rowstep = (size_t)128 * K;
  const int ldst0 = tid * 8;

  // ds_read: swizzled slot is a per-lane constant (row ≡ laneR mod 8)
  const int sprime = laneS ^ ((laneR >> 1) & 3);
  const int aoff = (wm * 128 + laneR) * 32 + sprime * 8;     // + ks*8192 + frag*512
  const int boff = 16384 + (wn * 64 + laneR) * 32 + sprime * 8;

  f32x4 acc[8][4] = {};
  bf16x8 afrX[4], afrY[4], bfrX[4], bfrY[4];

  #define STAGE_HT(SRC, KT, KS, DST)                                              \
    { gload_lds16((SRC) + (KT) * 64 + (KS) * 32,                                  \
                  (DST) + (KS) * 8192 + ldst0);                                   \
      gload_lds16((SRC) + (KT) * 64 + (KS) * 32 + rowstep,                        \
                  (DST) + (KS) * 8192 + 4096 + ldst0); }
  #define SBAR  __builtin_amdgcn_sched_barrier(0)
  #define MFMA16(ACCBASE, AF, BF)                                                 \
    _Pragma("unroll")                                                             \
    for (int ii = 0; ii < 4; ++ii)                                                \
      _Pragma("unroll")                                                           \
      for (int j = 0; j < 4; ++j)                                                 \
        acc[(ACCBASE) + ii][j] =                                                  \
            __builtin_amdgcn_mfma_f32_16x16x32_bf16(AF[ii], BF[j], acc[(ACCBASE) + ii][j], 0, 0, 0);

  // ---- prologue: 6 HTs in order; confirm k0(0); pre-read p0 frags ----
  {
    ushort* b0 = lds;
    ushort* b1 = lds + 32768;
    STAGE_HT(Asrc0, 0, 0, b0);              // HT1
    STAGE_HT(Bsrc0, 0, 0, b0 + 16384);      // HT2
    STAGE_HT(Asrc0, 0, 1, b0);              // HT3
    STAGE_HT(Bsrc0, 0, 1, b0 + 16384);      // HT4
    STAGE_HT(Asrc0, 1, 0, b1);              // HT5
    STAGE_HT(Bsrc0, 1, 0, b1 + 16384);      // HT6
  }
  asm volatile("s_waitcnt vmcnt(8)" ::: "memory");   // HT1-2 (k0(0) mine) done
  SBAR;
  __builtin_amdgcn_s_barrier();                      // block-wide: k0(0) present
  SBAR;
  #pragma unroll
  for (int j = 0; j < 4; ++j)
    bfrX[j] = *(const bf16x8*)(lds + boff + j * 512);
  #pragma unroll
  for (int ii = 0; ii < 4; ++ii)
    afrX[ii] = *(const bf16x8*)(lds + aoff + ii * 512);

  for (int t = 0; t < NT; ++t) {
    ushort* cbuf = lds + (t & 1) * 32768;
    ushort* nbuf = lds + ((t & 1) ^ 1) * 32768;
    const int t1 = (t + 1 < NT) ? t + 1 : t;   // clamped: tail stages are dead stores
    const int t2 = (t + 2 < NT) ? t + 2 : t;

    // ===== p0: MFMA(afrX,bfrX) ; prefetch afrY = cbuf k0 A ih1 =====
    STAGE_HT(Asrc0, t1, 1, nbuf);
    asm volatile("s_waitcnt vmcnt(6)" ::: "memory");  // k1(t) mine confirmed
    SBAR;
    #pragma unroll
    for (int ii = 0; ii < 4; ++ii)
      afrY[ii] = *(const bf16x8*)(cbuf + aoff + (4 + ii) * 512);
    SBAR;
    __builtin_amdgcn_s_setprio(1);
    MFMA16(0, afrX, bfrX);
    __builtin_amdgcn_s_setprio(0);
    SBAR;
    __builtin_amdgcn_s_barrier();                     // k1(t) block-wide
    SBAR;

    // ===== p1: MFMA(afrY,bfrX) ; prefetch bfrY,afrX = cbuf k1 =====
    STAGE_HT(Bsrc0, t1, 1, nbuf + 16384);
    SBAR;
    #pragma unroll
    for (int j = 0; j < 4; ++j)
      bfrY[j] = *(const bf16x8*)(cbuf + 8192 + boff + j * 512);
    #pragma unroll
    for (int ii = 0; ii < 4; ++ii)
      afrX[ii] = *(const bf16x8*)(cbuf + 8192 + aoff + ii * 512);
    SBAR;
    __builtin_amdgcn_s_setprio(1);
    MFMA16(4, afrY, bfrX);
    __builtin_amdgcn_s_setprio(0);
    SBAR;
    __builtin_amdgcn_s_barrier();
    SBAR;

    // ===== p2: MFMA(afrX,bfrY) ; prefetch afrY = cbuf k1 A ih1 =====
    STAGE_HT(Asrc0, t2, 0, cbuf);                     // cbuf k0 dead (read p0/p1 done)
    asm volatile("s_waitcnt vmcnt(6)" ::: "memory");  // k0(t+1) mine confirmed
    SBAR;
    #pragma unroll
    for (int ii = 0; ii < 4; ++ii)
      afrY[ii] = *(const bf16x8*)(cbuf + 8192 + aoff + (4 + ii) * 512);
    SBAR;
    __builtin_amdgcn_s_setprio(1);
    MFMA16(0, afrX, bfrY);
    __builtin_amdgcn_s_setprio(0);
    SBAR;
    __builtin_amdgcn_s_barrier();                     // k0(t+1) block-wide
    SBAR;

    // ===== p3: MFMA(afrY,bfrY) ; prefetch bfrX,afrX = nbuf k0 (next tile p0) =====
    STAGE_HT(Bsrc0, t2, 0, cbuf + 16384);
    SBAR;
    #pragma unroll
    for (int j = 0; j < 4; ++j)
      bfrX[j] = *(const bf16x8*)(nbuf + boff + j * 512);
    #pragma unroll
    for (int ii = 0; ii < 4; ++ii)
      afrX[ii] = *(const bf16x8*)(nbuf + aoff + ii * 512);
    SBAR;
    __builtin_amdgcn_s_setprio(1);
    MFMA16(4, afrY, bfrY);
    __builtin_amdgcn_s_setprio(0);
    SBAR;
    __builtin_amdgcn_s_barrier();
    SBAR;
  }
  #undef STAGE_HT
  #undef MFMA16
  asm volatile("s_waitcnt vmcnt(0)" ::: "memory");    // drain dead tail stages

  // ---- epilogue: C/D layout col=lane&15, row=(lane>>4)*4+r ----
  #pragma unroll
  for (int i = 0; i < 8; ++i) {
    const int grow0 = m0 + wm * 128 + i * 16 + (laneS << 2);
    #pragma unroll
    for (int j = 0; j < 4; ++j) {
      const int gcol = n0 + wn * 64 + j * 16 + laneR;
      #pragma unroll
      for (int r = 0; r < 4; ++r) {
        float v = acc[i][j][r];
        if (MODE == 0) {
          if (gcol < 1536) v = (v > 0.f) ? (v + 1.f) : __expf(v);   // phi on q,k
          reinterpret_cast<ushort*>(C)[(size_t)(grow0 + r) * N + gcol] = f2bf(v);
        } else {
          reinterpret_cast<float*>(C)[(size_t)(grow0 + r) * N + gcol] = v + bias[gcol];
        }
      }
    }
  }
}

// ---------------- kv partial: per (b,h,s-split) outer-product accumulation ----------
__global__ __launch_bounds__(256) void kv_partial(const ushort* __restrict__ qkv,
                                                  float* __restrict__ kv_part,
                                                  float* __restrict__ ks_part) {
  const int blk = blockIdx.x;          // 384*4
  const int bh = blk >> 2, sp = blk & 3;
  const int b = bh / 12, h = bh % 12;
  const int tid = threadIdx.x;
  __shared__ ushort Ks[32 * 64];
  __shared__ ushort Vs[32 * 64];
  float acc[4][4] = {};                // [m][dq]
  float kacc[4] = {};
  const int dq0 = (tid & 15) * 4, mq0 = (tid >> 4) * 4;
  const int r = tid >> 3, o = tid & 7;
  for (int st = 0; st < 256; st += 32) {
    const int s0 = sp * 256 + st;
    __syncthreads();
    const size_t rowbase = (size_t)(b * 1024 + s0 + r) * 2304 + h * 64 + o * 8;
    gload_lds16(qkv + rowbase + 768,  &Ks[tid * 8]);
    gload_lds16(qkv + rowbase + 1536, &Vs[tid * 8]);
    asm volatile("s_waitcnt vmcnt(0)" ::: "memory");
    __syncthreads();
    #pragma unroll 8
    for (int s = 0; s < 32; ++s) {
      short4 kk = *reinterpret_cast<const short4*>(&Ks[s * 64 + dq0]);
      short4 vv = *reinterpret_cast<const short4*>(&Vs[s * 64 + mq0]);
      float kf[4] = { bf2f((ushort)kk.x), bf2f((ushort)kk.y), bf2f((ushort)kk.z), bf2f((ushort)kk.w) };
      float vf[4] = { bf2f((ushort)vv.x), bf2f((ushort)vv.y), bf2f((ushort)vv.z), bf2f((ushort)vv.w) };
      #pragma unroll
      for (int jm = 0; jm < 4; ++jm)
        #pragma unroll
        for (int id = 0; id < 4; ++id)
          acc[jm][id] += vf[jm] * kf[id];
      if (mq0 == 0) {
        #pragma unroll
        for (int id = 0; id < 4; ++id) kacc[id] += kf[id];
      }
    }
  }
  float* kvp = kv_part + ((size_t)sp * 384 + bh) * 4096;
  #pragma unroll
  for (int jm = 0; jm < 4; ++jm)
    #pragma unroll
    for (int id = 0; id < 4; ++id)
      kvp[(mq0 + jm) * 64 + dq0 + id] = acc[jm][id];
  if (mq0 == 0) {
    #pragma unroll
    for (int id = 0; id < 4; ++id)
      ks_part[((size_t)sp * 384 + bh) * 64 + dq0 + id] = kacc[id];
  }
}

// ---------------- reduce splits: kv -> bf16 [bh][m][dq], ksum += 1.0 (pad token) ----
__global__ __launch_bounds__(256) void kv_reduce(const float* __restrict__ kv_part,
                                                 const float* __restrict__ ks_part,
                                                 ushort* __restrict__ kv_bf,
                                                 float* __restrict__ ksum) {
  int i = blockIdx.x * 256 + threadIdx.x;
  if (i < 384 * 4096) {
    float s = 0.f;
    #pragma unroll
    for (int p = 0; p < 4; ++p) s += kv_part[(size_t)p * (384 * 4096) + i];
    kv_bf[i] = f2bf(s);
  }
  if (i < 384 * 64) {
    float s = 1.0f;    // phi(0)=1 contribution of the zero padding token
    #pragma unroll
    for (int p = 0; p < 4; ++p) s += ks_part[(size_t)p * (384 * 64) + i];
    ksum[i] = s;
  }
}

// ---------------- attention: out[t][h*64+m] = z[t] * sum_dq q[t][dq]*kv[dq][m] -------
__global__ __launch_bounds__(256) void attn_kernel(const ushort* __restrict__ qkv,
                                                   const ushort* __restrict__ kv_bf,
                                                   const float* __restrict__ ksum,
                                                   ushort* __restrict__ attn) {
  const int blk = blockIdx.x;          // 384*8
  const int bh = blk >> 3, tb = blk & 7;
  const int b = bh / 12, h = bh % 12;
  const int row0 = b * 1024 + tb * 128;
  __shared__ ushort Qs[128 * 64];
  __shared__ ushort KVs[64 * 64];      // [m][dq]
  __shared__ float zs[128];
  __shared__ float ks_lds[64];
  const int tid = threadIdx.x;
  const int lane = tid & 63, w = tid >> 6;
  #pragma unroll
  for (int j = 0; j < 4; ++j) {
    int c = j * 256 + tid;
    gload_lds16(qkv + (size_t)(row0 + (c >> 3)) * 2304 + h * 64 + (c & 7) * 8, &Qs[c * 8]);
  }
  #pragma unroll
  for (int j = 0; j < 2; ++j) {
    int c = j * 256 + tid;
    gload_lds16(kv_bf + (size_t)bh * 4096 + c * 8, &KVs[c * 8]);
  }
  if (tid < 64) ks_lds[tid] = ksum[bh * 64 + tid];
  asm volatile("s_waitcnt vmcnt(0)" ::: "memory");
  __syncthreads();
  if (tid < 128) {
    float d = 0.f;
    #pragma unroll 8
    for (int e = 0; e < 64; ++e) d += bf2f(Qs[tid * 64 + e]) * ks_lds[e];
    zs[tid] = 1.f / (d + 1e-6f);
  }
  __syncthreads();
  f32x4 acc[2][4] = {};
  #pragma unroll
  for (int ks = 0; ks < 2; ++ks) {
    bf16x8 a[2], bb[4];
    #pragma unroll
    for (int i = 0; i < 2; ++i)
      a[i] = *reinterpret_cast<const bf16x8*>(&Qs[(w * 32 + i * 16 + (lane & 15)) * 64 + ks * 32 + (lane >> 4) * 8]);
    #pragma unroll
    for (int j = 0; j < 4; ++j)
      bb[j] = *reinterpret_cast<const bf16x8*>(&KVs[(j * 16 + (lane & 15)) * 64 + ks * 32 + (lane >> 4) * 8]);
    #pragma unroll
    for (int i = 0; i < 2; ++i)
      #pragma unroll
      for (int j = 0; j < 4; ++j)
        acc[i][j] = __builtin_amdgcn_mfma_f32_16x16x32_bf16(a[i], bb[j], acc[i][j], 0, 0, 0);
  }
  #pragma unroll
  for (int i = 0; i < 2; ++i) {
    const int t0 = w * 32 + i * 16 + ((lane >> 4) << 2);
    #pragma unroll
    for (int j = 0; j < 4; ++j) {
      const int m = j * 16 + (lane & 15);
      #pragma unroll
      for (int r = 0; r < 4; ++r) {
        float v = acc[i][j][r] * zs[t0 + r];
        attn[(size_t)(row0 + t0 + r) * 768 + h * 64 + m] = f2bf(v);
      }
    }
  }
}

// ---------------- launch ----------------
extern "C" void kernel_launch(void* const* d_in, const int* in_sizes, int n_in,
                              void* d_out, int out_size, void* d_ws, size_t ws_size,
                              hipStream_t stream) {
  (void)in_sizes; (void)n_in; (void)out_size; (void)ws_size;
  const float* x    = (const float*)d_in[0];
  const float* Wqkv = (const float*)d_in[1];
  const float* Wout = (const float*)d_in[2];
  const float* bout = (const float*)d_in[3];
  float* out = (float*)d_out;
  char* ws = (char*)d_ws;

  // workspace layout (total ~210 MB); region 0 is reused by 3 time-disjoint buffers
  ushort* xbf    = (ushort*)(ws);               // 50,331,648 B : x bf16 [32768][768]
  ushort* wqkvT  = (ushort*)(ws + 50331648);    //  3,538,944 B : W_qkv^T bf16 [2304][768]
  ushort* woutT  = (ushort*)(ws + 53870592);    //  1,179,648 B : W_out^T bf16 [768][768]
  ushort* qkv    = (ushort*)(ws + 55050240);    // 150,994,944 B: phi(q)|phi(k)|v bf16 [32768][2304]
  float*  ksp    = (float*) (ws + 206045184);   //    393,216 B : ksum partials [4][384][64]
  ushort* kvbf   = (ushort*)(ws + 206438400);   //  3,145,728 B : kv bf16 [384][64m][64dq]
  float*  ksum   = (float*) (ws + 209584128);   //     98,304 B : ksum+1 [384][64]
  float*  kvpart = (float*)(ws);                // 25,165,824 B : overlays xbf (dead after gemm1)
  ushort* attn   = (ushort*)(ws);               // 50,331,648 B : overlays kvpart (dead after kv_reduce)

  static const int LDS_BYTES = 131072;
  hipFuncSetAttribute(reinterpret_cast<const void*>(&gemm256<0>),
                      hipFuncAttributeMaxDynamicSharedMemorySize, LDS_BYTES);
  hipFuncSetAttribute(reinterpret_cast<const void*>(&gemm256<1>),
                      hipFuncAttributeMaxDynamicSharedMemorySize, LDS_BYTES);

  cvt_f32_bf16<<<24576, 256, 0, stream>>>(x, xbf, 6291456);
  transpose_cvt<<<dim3(72, 24), 256, 0, stream>>>(Wqkv, wqkvT, 768, 2304);
  transpose_cvt<<<dim3(24, 24), 256, 0, stream>>>(Wout, woutT, 768, 768);
  // GEMM1: M=32768 (nby=128), N=2304 (nbx=9) -> nwg=1152, cpx=144
  gemm256<0><<<1152, 512, LDS_BYTES, stream>>>(xbf, wqkvT, qkv, nullptr, 2304, 768, 9, 144);
  kv_partial<<<1536, 256, 0, stream>>>(qkv, kvpart, ksp);
  kv_reduce<<<6144, 256, 0, stream>>>(kvpart, ksp, kvbf, ksum);
  attn_kernel<<<3072, 256, 0, stream>>>(qkv, kvbf, ksum, attn);
  // GEMM2: M=32768 (nby=128), N=768 (nbx=3) -> nwg=384, cpx=48
  gemm256<1><<<384, 512, LDS_BYTES, stream>>>(attn, woutT, out, bout, 768, 768, 3, 48);
}